// Round 8
// baseline (313.277 us; speedup 1.0000x reference)
//
#include <hip/hip_runtime.h>
#include <cstdint>
#include <cstddef>

typedef unsigned short u16;
typedef __attribute__((ext_vector_type(8))) short bf16x8;
typedef __attribute__((ext_vector_type(4))) float f32x4;

__device__ __forceinline__ float bf2f(u16 u) {
  return __uint_as_float(((unsigned)u) << 16);
}
__device__ __forceinline__ u16 f2bf(float f) {
  unsigned x = __float_as_uint(f);
  return (u16)((x + 0x7fffu + ((x >> 16) & 1u)) >> 16);
}
// packed RNE f32x2 -> bf16x2 (gfx950)
__device__ __forceinline__ unsigned pk2(float a, float b) {
  unsigned r;
  asm("v_cvt_pk_bf16_f32 %0, %1, %2" : "=v"(r) : "v"(a), "v"(b));
  return r;
}

// X region: 64 tiles of [dl:16][x:64] u16 (128 KiB), XOR-swizzled.
__device__ __forceinline__ int taddr(int g, int dl, int x) {
  return (((g << 4) + dl) << 6) | (x ^ (((g ^ dl) & 7) << 3));
}
// wave-private P scratch: 16 waves x 2 KiB, after the X region.
__device__ __forceinline__ int saddr(int w, int dl, int y) {
  return 65536 + ((((w << 4) + dl) << 6) | (y ^ ((dl & 7) << 3)));
}

// pre-packed bf16 weight A-fragment: flat row = gr*16 + (lane&15), k = ks*32 + (lane>>4)*8 + e
__device__ __forceinline__ bf16x8 apk_frag(const u16* __restrict__ APK, int mat, int gr,
                                           int ks, int lane) {
  return *(const bf16x8*)&APK[(((((mat << 8) + gr) << 1) + ks) << 9) + lane * 8];
}
// B-fragment from an X tile: col = lane&15 (= dl), k-run = (ks*4 + lane>>4)*8 over x
__device__ __forceinline__ bf16x8 xfrag(const ushort* Xs, int g, int ks, int lane) {
  return *(const bf16x8*)&Xs[taddr(g, lane & 15, ((ks << 2) + (lane >> 4)) << 3)];
}
__device__ __forceinline__ bf16x8 sfrag(const ushort* Xs, int w, int ks, int lane) {
  return *(const bf16x8*)&Xs[saddr(w, lane & 15, ((ks << 2) + (lane >> 4)) << 3)];
}

// one 64-row-weight x tile matmul: acc[grp] rows = grp*16 + (lane>>4)*4 + r, cols = dl = lane&15
__device__ __forceinline__ void wmm(const u16* __restrict__ APK, int mat, int unit,
                                    bf16x8 f0, bf16x8 f1, int lane, f32x4 acc[4]) {
#pragma unroll
  for (int grp = 0; grp < 4; ++grp) {
    acc[grp] = __builtin_amdgcn_mfma_f32_16x16x32_bf16(
        apk_frag(APK, mat, unit * 4 + grp, 0, lane), f0, acc[grp], 0, 0, 0);
    acc[grp] = __builtin_amdgcn_mfma_f32_16x16x32_bf16(
        apk_frag(APK, mat, unit * 4 + grp, 1, lane), f1, acc[grp], 0, 0, 0);
  }
}

// ---------------------------------------------------------------------------
// k_prep: pack {M1L,M1R,M2L,M2R} into A-fragment order bf16 (2 MB, in d_ws).
// mat 0 packs k-slot kk <- W[row][((kk&7)<<3)|(kk>>3)] to match the stage-in
// xpos digit-swap permutation (involution).
// ---------------------------------------------------------------------------
__global__ __launch_bounds__(256) void k_prep(const float* __restrict__ W0,
                                              const float* __restrict__ W1,
                                              const float* __restrict__ W2,
                                              const float* __restrict__ W3,
                                              u16* __restrict__ APK) {
  const int gr = blockIdx.x, mat = blockIdx.y;
  const float* W = (mat == 0) ? W0 : (mat == 1) ? W1 : (mat == 2) ? W2 : W3;
  const int t = threadIdx.x;
  const int lane = t & 63, ks = (t >> 6) & 1, half = t >> 7;
  const int row = gr * 16 + (lane & 15);
  const int k0 = ks * 32 + ((lane >> 4) << 3) + half * 4;
  ushort4 o;
  if (mat == 0) {
    o.x = f2bf(W[row * 64 + ((((k0 + 0) & 7) << 3) | ((k0 + 0) >> 3))]);
    o.y = f2bf(W[row * 64 + ((((k0 + 1) & 7) << 3) | ((k0 + 1) >> 3))]);
    o.z = f2bf(W[row * 64 + ((((k0 + 2) & 7) << 3) | ((k0 + 2) >> 3))]);
    o.w = f2bf(W[row * 64 + ((((k0 + 3) & 7) << 3) | ((k0 + 3) >> 3))]);
  } else {
    float4 v = *(const float4*)&W[row * 64 + k0];
    o.x = f2bf(v.x); o.y = f2bf(v.y); o.z = f2bf(v.z); o.w = f2bf(v.w);
  }
  *(ushort4*)&APK[((((((mat << 8) + gr) << 1) + ks) << 6) + lane) * 8 + half * 4] = o;
}

// ---------------------------------------------------------------------------
// k_mega v3: fused 4-stage monarch chain for one (d-quarter, bh) slice.
// 1024 threads (16 waves, 4 tiles/wave), 160 KiB LDS, grid = 256 (1 block/CU).
// __launch_bounds__(1024, 4): 16 waves/CU = 4 waves/EU -> VGPR cap 128 (no spill).
// ---------------------------------------------------------------------------
__global__ __launch_bounds__(1024, 4) void k_mega(const float* __restrict__ q,
                                                  const float* __restrict__ keys,
                                                  const float* __restrict__ vals,
                                                  const u16* __restrict__ APK,
                                                  const float* __restrict__ b1,
                                                  const float* __restrict__ b2,
                                                  float* __restrict__ out) {
  __shared__ ushort Xs[81920];  // 160 KiB exactly (128K X + 32K P-scratch)
  const int bid = blockIdx.x;
  const int dq = bid >> 6;
  const int bh = ((bid & 7) << 3) | ((bid >> 3) & 7);  // 4 dq-blocks of a bh share an XCD
  const int b = bh >> 3, h = bh & 7;
  const int tid = threadIdx.x, w = tid >> 6, l = tid & 63;
  const size_t inbase = (size_t)b * 4096 * 512 + h * 64 + dq * 16;  // + s*512 + dl

  // ---- stage-in: q -> tile g=B holds [dl][xpos], xpos = ((m&7)<<3)|(m>>3)
  {
    const int a = w & 7, c0 = (w >> 3) << 2;
    const int x0 = (a << 3) | c0;  // xpos run of 4 for this wave
#pragma unroll
    for (int hh = 0; hh < 2; ++hh) {
      float st[4][8];
#pragma unroll
      for (int j = 0; j < 4; ++j) {
        const int m = ((c0 + j) << 3) + a;
        const float* qr = q + inbase + (size_t)(m * 64 + l) * 512 + hh * 8;
        float4 v0 = *(const float4*)(qr);
        float4 v1 = *(const float4*)(qr + 4);
        st[j][0] = v0.x; st[j][1] = v0.y; st[j][2] = v0.z; st[j][3] = v0.w;
        st[j][4] = v1.x; st[j][5] = v1.y; st[j][6] = v1.z; st[j][7] = v1.w;
      }
#pragma unroll
      for (int d8 = 0; d8 < 8; ++d8) {
        const int dl = (hh << 3) + d8;
        uint2 pw;
        pw.x = pk2(st[0][d8], st[1][d8]);
        pw.y = pk2(st[2][d8], st[3][d8]);
        *(uint2*)&Xs[taddr(l, dl, x0)] = pw;
      }
    }
  }
  __syncthreads();

  bf16x8 fr[4][2];

  // ---- S1: T1[(n,B)] = sum_m L1[B][n][m] q[(m,B)] -> tile n, x=B
#pragma unroll
  for (int u = 0; u < 4; ++u) {
    fr[u][0] = xfrag(Xs, (w << 2) + u, 0, l);
    fr[u][1] = xfrag(Xs, (w << 2) + u, 1, l);
  }
  __syncthreads();
#pragma unroll
  for (int u = 0; u < 4; ++u) {
    const int B = (w << 2) + u;
    f32x4 acc[4] = {};
    wmm(APK, 0, B, fr[u][0], fr[u][1], l, acc);
#pragma unroll
    for (int grp = 0; grp < 4; ++grp)
#pragma unroll
      for (int r = 0; r < 4; ++r) {
        const int n = (grp << 4) + ((l >> 4) << 2) + r;
        Xs[taddr(n, l & 15, B)] = f2bf(acc[grp][r]);
      }
  }
  __syncthreads();

  // ---- S2+S3 per n: P = (R1[n]·T1)∘k + b1 (wave scratch); T2 = L2[n]·P -> tile n2, x=n
#pragma unroll
  for (int u = 0; u < 4; ++u) {
    fr[u][0] = xfrag(Xs, (w << 2) + u, 0, l);
    fr[u][1] = xfrag(Xs, (w << 2) + u, 1, l);
  }
  __syncthreads();
#pragma unroll
  for (int u = 0; u < 4; ++u) {
    const int n = (w << 2) + u;
    float kv[16], bb[16];
#pragma unroll
    for (int grp = 0; grp < 4; ++grp)
#pragma unroll
      for (int r = 0; r < 4; ++r) {
        const int y = (grp << 4) + ((l >> 4) << 2) + r;
        kv[(grp << 2) + r] = keys[inbase + (size_t)((y << 6) + n) * 512 + (l & 15)];
        bb[(grp << 2) + r] = b1[(y << 6) + n];
      }
    f32x4 acc[4] = {};
    wmm(APK, 1, n, fr[u][0], fr[u][1], l, acc);
#pragma unroll
    for (int grp = 0; grp < 4; ++grp)
#pragma unroll
      for (int r = 0; r < 4; ++r) {
        const int y = (grp << 4) + ((l >> 4) << 2) + r;
        Xs[saddr(w, l & 15, y)] = f2bf(acc[grp][r] * kv[(grp << 2) + r] + bb[(grp << 2) + r]);
      }
    bf16x8 s0 = sfrag(Xs, w, 0, l);
    bf16x8 s1 = sfrag(Xs, w, 1, l);
    f32x4 acc2[4] = {};
    wmm(APK, 2, n, s0, s1, l, acc2);
#pragma unroll
    for (int grp = 0; grp < 4; ++grp)
#pragma unroll
      for (int r = 0; r < 4; ++r) {
        const int n2 = (grp << 4) + ((l >> 4) << 2) + r;
        Xs[taddr(n2, l & 15, n)] = f2bf(acc2[grp][r]);
      }
  }
  __syncthreads();

  // ---- S4 per n2: Y = (R2[n2]·T2 + b2)∘v -> tile i2, x=n2
#pragma unroll
  for (int u = 0; u < 4; ++u) {
    fr[u][0] = xfrag(Xs, (w << 2) + u, 0, l);
    fr[u][1] = xfrag(Xs, (w << 2) + u, 1, l);
  }
  __syncthreads();
#pragma unroll
  for (int u = 0; u < 4; ++u) {
    const int n2 = (w << 2) + u;
    float vv[16], bb[16];
#pragma unroll
    for (int grp = 0; grp < 4; ++grp)
#pragma unroll
      for (int r = 0; r < 4; ++r) {
        const int i2 = (grp << 4) + ((l >> 4) << 2) + r;
        vv[(grp << 2) + r] = vals[inbase + (size_t)((i2 << 6) + n2) * 512 + (l & 15)];
        bb[(grp << 2) + r] = b2[(i2 << 6) + n2];
      }
    f32x4 acc[4] = {};
    wmm(APK, 3, n2, fr[u][0], fr[u][1], l, acc);
#pragma unroll
    for (int grp = 0; grp < 4; ++grp)
#pragma unroll
      for (int r = 0; r < 4; ++r) {
        const int i2 = (grp << 4) + ((l >> 4) << 2) + r;
        Xs[taddr(i2, l & 15, n2)] = f2bf((acc[grp][r] + bb[(grp << 2) + r]) * vv[(grp << 2) + r]);
      }
  }
  __syncthreads();

  // ---- out: out[bh][d][s] fp32, fully coalesced; wave w owns d-row dl = w
  {
    float* orow = out + ((size_t)bh * 64 + (dq << 4) + w) * 4096;
#pragma unroll
    for (int o = 0; o < 16; ++o) {
      const int s4 = (o << 8) + (l << 2);
      uint2 rv = *(const uint2*)&Xs[taddr(s4 >> 6, w, s4 & 63)];
      float4 ov;
      ov.x = bf2f((u16)(rv.x & 0xffffu));
      ov.y = bf2f((u16)(rv.x >> 16));
      ov.z = bf2f((u16)(rv.y & 0xffffu));
      ov.w = bf2f((u16)(rv.y >> 16));
      *(float4*)(orow + s4) = ov;
    }
  }
}

// ---------------------------------------------------------------------------
extern "C" void kernel_launch(void* const* d_in, const int* in_sizes, int n_in,
                              void* d_out, int out_size, void* d_ws, size_t ws_size,
                              hipStream_t stream) {
  const float* q   = (const float*)d_in[0];
  const float* k   = (const float*)d_in[1];
  const float* v   = (const float*)d_in[2];
  const float* M1L = (const float*)d_in[3];
  const float* M1R = (const float*)d_in[4];
  const float* M2L = (const float*)d_in[5];
  const float* M2R = (const float*)d_in[6];
  const float* b1  = (const float*)d_in[7];
  const float* b2  = (const float*)d_in[8];

  u16* APK = (u16*)d_ws;  // 2 MB packed weights

  k_prep<<<dim3(256, 4), 256, 0, stream>>>(M1L, M1R, M2L, M2R, APK);
  k_mega<<<256, 1024, 0, stream>>>(q, k, v, APK, b1, b2, (float*)d_out);
}

// Round 9
// 304.668 us; speedup vs baseline: 1.0283x; 1.0283x over previous
//
#include <hip/hip_runtime.h>
#include <cstdint>
#include <cstddef>

typedef unsigned short u16;
typedef __attribute__((ext_vector_type(8))) short bf16x8;
typedef __attribute__((ext_vector_type(4))) float f32x4;

__device__ __forceinline__ float bf2f(u16 u) {
  return __uint_as_float(((unsigned)u) << 16);
}
__device__ __forceinline__ u16 f2bf(float f) {
  unsigned x = __float_as_uint(f);
  return (u16)((x + 0x7fffu + ((x >> 16) & 1u)) >> 16);
}
// packed RNE f32x2 -> bf16x2 (gfx950): result low16 = a, high16 = b
__device__ __forceinline__ unsigned pk2(float a, float b) {
  unsigned r;
  asm("v_cvt_pk_bf16_f32 %0, %1, %2" : "=v"(r) : "v"(a), "v"(b));
  return r;
}
__device__ __forceinline__ float pkget(unsigned u, int hi) {
  return bf2f((u16)(hi ? (u >> 16) : (u & 0xffffu)));
}

// X region: 64 tiles of [dl:16][x:64] u16 (128 KiB), XOR-swizzled.
__device__ __forceinline__ int taddr(int g, int dl, int x) {
  return (((g << 4) + dl) << 6) | (x ^ (((g ^ dl) & 7) << 3));
}
// wave-private P scratch: 8 waves x 2 KiB, after the X region.
__device__ __forceinline__ int saddr(int w, int dl, int y) {
  return 65536 + ((((w << 4) + dl) << 6) | (y ^ ((dl & 7) << 3)));
}

// pre-packed bf16 weight fragment: flat row = gr*16 + (lane&15), k = ks*32 + (lane>>4)*8 + e
__device__ __forceinline__ bf16x8 apk_frag(const u16* __restrict__ APK, int mat, int gr,
                                           int ks, int lane) {
  return *(const bf16x8*)&APK[(((((mat << 8) + gr) << 1) + ks) << 9) + lane * 8];
}
// B-fragment from an X tile: col = lane&15 (= dl), k-run = (ks*4 + lane>>4)*8 over x
__device__ __forceinline__ bf16x8 xfrag(const ushort* Xs, int g, int ks, int lane) {
  return *(const bf16x8*)&Xs[taddr(g, lane & 15, ((ks << 2) + (lane >> 4)) << 3)];
}
__device__ __forceinline__ bf16x8 sfrag(const ushort* Xs, int w, int ks, int lane) {
  return *(const bf16x8*)&Xs[saddr(w, lane & 15, ((ks << 2) + (lane >> 4)) << 3)];
}

// acc[grp] rows = grp*16 + (lane>>4)*4 + r (over weight flat-row), cols = dl = lane&15
__device__ __forceinline__ void wmm(const u16* __restrict__ APK, int mat, int unit,
                                    bf16x8 f0, bf16x8 f1, int lane, f32x4 acc[4]) {
#pragma unroll
  for (int grp = 0; grp < 4; ++grp) {
    acc[grp] = __builtin_amdgcn_mfma_f32_16x16x32_bf16(
        apk_frag(APK, mat, unit * 4 + grp, 0, lane), f0, acc[grp], 0, 0, 0);
    acc[grp] = __builtin_amdgcn_mfma_f32_16x16x32_bf16(
        apk_frag(APK, mat, unit * 4 + grp, 1, lane), f1, acc[grp], 0, 0, 0);
  }
}

// ---------------------------------------------------------------------------
// k_prep: pack {M1L,M1R,M2L,M2R} into fragment order bf16 (2 MB, in d_ws).
// mat 0 packs k-slot kk <- W[row][((kk&7)<<3)|(kk>>3)] (stage-in xpos involution).
// ---------------------------------------------------------------------------
__global__ __launch_bounds__(256) void k_prep(const float* __restrict__ W0,
                                              const float* __restrict__ W1,
                                              const float* __restrict__ W2,
                                              const float* __restrict__ W3,
                                              u16* __restrict__ APK) {
  const int gr = blockIdx.x, mat = blockIdx.y;
  const float* W = (mat == 0) ? W0 : (mat == 1) ? W1 : (mat == 2) ? W2 : W3;
  const int t = threadIdx.x;
  const int lane = t & 63, ks = (t >> 6) & 1, half = t >> 7;
  const int row = gr * 16 + (lane & 15);
  const int k0 = ks * 32 + ((lane >> 4) << 3) + half * 4;
  ushort4 o;
  if (mat == 0) {
    o.x = f2bf(W[row * 64 + ((((k0 + 0) & 7) << 3) | ((k0 + 0) >> 3))]);
    o.y = f2bf(W[row * 64 + ((((k0 + 1) & 7) << 3) | ((k0 + 1) >> 3))]);
    o.z = f2bf(W[row * 64 + ((((k0 + 2) & 7) << 3) | ((k0 + 2) >> 3))]);
    o.w = f2bf(W[row * 64 + ((((k0 + 3) & 7) << 3) | ((k0 + 3) >> 3))]);
  } else {
    float4 v = *(const float4*)&W[row * 64 + k0];
    o.x = f2bf(v.x); o.y = f2bf(v.y); o.z = f2bf(v.z); o.w = f2bf(v.w);
  }
  *(ushort4*)&APK[((((((mat << 8) + gr) << 1) + ks) << 6) + lane) * 8 + half * 4] = o;
}

// ---------------------------------------------------------------------------
// k_mega v4: fused 4-stage monarch chain for one (d-quarter, bh) slice.
// 512 threads (8 waves, 8 tiles/wave), 144 KiB LDS, grid 256 (1 block/CU).
// __launch_bounds__(512, 2): 8 waves x 256 regs = full file, no spill possible
// if demand <= 256; measured demand ~116.
// ---------------------------------------------------------------------------
__global__ __launch_bounds__(512, 2) void k_mega(const float* __restrict__ q,
                                                 const float* __restrict__ keys,
                                                 const float* __restrict__ vals,
                                                 const u16* __restrict__ APK,
                                                 const float* __restrict__ b1,
                                                 const float* __restrict__ b2,
                                                 float* __restrict__ out) {
  __shared__ ushort Xs[73728];  // 144 KiB: 128K X + 16K P-scratch
  const int bid = blockIdx.x;
  const int dq = bid >> 6;
  const int bh = bid & 63;  // all 4 dq-blocks of a bh land on XCD bh%8 (grid 256, rr dispatch)
  const int b = bh >> 3, h = bh & 7;
  const int tid = threadIdx.x, w = tid >> 6, l = tid & 63;
  const size_t inbase = (size_t)b * 4096 * 512 + h * 64 + dq * 16;  // + s*512 + dl

  // ---- stage-in: q -> tile g=B holds [dl][xpos], xpos = ((m&7)<<3)|(m>>3).
  // wave w covers m = j*8 + w (j=0..7) -> xpos = (w<<3)|j; quarter-chunks keep regs low.
#pragma unroll
  for (int hq = 0; hq < 2; ++hq) {        // j-quad
#pragma unroll
    for (int hh2 = 0; hh2 < 2; ++hh2) {   // d-half
      float st[4][8];
#pragma unroll
      for (int j4 = 0; j4 < 4; ++j4) {
        const int m = (((hq << 2) + j4) << 3) + w;
        const float* qr = q + inbase + (size_t)(m * 64 + l) * 512 + hh2 * 8;
        float4 v0 = *(const float4*)(qr);
        float4 v1 = *(const float4*)(qr + 4);
        st[j4][0] = v0.x; st[j4][1] = v0.y; st[j4][2] = v0.z; st[j4][3] = v0.w;
        st[j4][4] = v1.x; st[j4][5] = v1.y; st[j4][6] = v1.z; st[j4][7] = v1.w;
      }
      const int x0 = (w << 3) | (hq << 2);
#pragma unroll
      for (int d8 = 0; d8 < 8; ++d8) {
        const int dl = (hh2 << 3) + d8;
        uint2 pw;
        pw.x = pk2(st[0][d8], st[1][d8]);
        pw.y = pk2(st[2][d8], st[3][d8]);
        *(uint2*)&Xs[taddr(l, dl, x0)] = pw;
      }
    }
  }
  __syncthreads();

  bf16x8 fr[8][2];

  // ---- S1: T1[(n,B)] = sum_m L1[B][n][m] q[(m,B)] -> tile n, x=B
#pragma unroll
  for (int u = 0; u < 8; ++u) {
    fr[u][0] = xfrag(Xs, w * 8 + u, 0, l);
    fr[u][1] = xfrag(Xs, w * 8 + u, 1, l);
  }
  __syncthreads();
#pragma unroll
  for (int u = 0; u < 8; ++u) {
    const int B = w * 8 + u;
    f32x4 acc[4] = {};
    wmm(APK, 0, B, fr[u][0], fr[u][1], l, acc);
#pragma unroll
    for (int grp = 0; grp < 4; ++grp)
#pragma unroll
      for (int r = 0; r < 4; ++r) {
        const int n = (grp << 4) + ((l >> 4) << 2) + r;
        Xs[taddr(n, l & 15, B)] = f2bf(acc[grp][r]);
      }
  }
  __syncthreads();

  // ---- S2+S3 per n: P = (R1[n]·T1)∘k + b1 (wave scratch); T2 = L2[n]·P -> tile n2, x=n
#pragma unroll
  for (int u = 0; u < 8; ++u) {
    fr[u][0] = xfrag(Xs, w * 8 + u, 0, l);
    fr[u][1] = xfrag(Xs, w * 8 + u, 1, l);
  }
  __syncthreads();
#pragma unroll
  for (int u = 0; u < 8; ++u) {
    const int n = w * 8 + u;
    unsigned kpk[8], bpk[8];
#pragma unroll
    for (int grp = 0; grp < 4; ++grp) {
      float kt[4], bt[4];
#pragma unroll
      for (int r = 0; r < 4; ++r) {
        const int y = (grp << 4) + ((l >> 4) << 2) + r;
        kt[r] = keys[inbase + (size_t)((y << 6) + n) * 512 + (l & 15)];
        bt[r] = b1[(y << 6) + n];
      }
      kpk[grp * 2] = pk2(kt[0], kt[1]); kpk[grp * 2 + 1] = pk2(kt[2], kt[3]);
      bpk[grp * 2] = pk2(bt[0], bt[1]); bpk[grp * 2 + 1] = pk2(bt[2], bt[3]);
    }
    f32x4 acc[4] = {};
    wmm(APK, 1, n, fr[u][0], fr[u][1], l, acc);
#pragma unroll
    for (int grp = 0; grp < 4; ++grp)
#pragma unroll
      for (int r = 0; r < 4; ++r) {
        const int y = (grp << 4) + ((l >> 4) << 2) + r;
        const float kf = pkget(kpk[grp * 2 + (r >> 1)], r & 1);
        const float bf = pkget(bpk[grp * 2 + (r >> 1)], r & 1);
        Xs[saddr(w, l & 15, y)] = f2bf(acc[grp][r] * kf + bf);
      }
    bf16x8 s0 = sfrag(Xs, w, 0, l);
    bf16x8 s1 = sfrag(Xs, w, 1, l);
    f32x4 acc2[4] = {};
    wmm(APK, 2, n, s0, s1, l, acc2);
#pragma unroll
    for (int grp = 0; grp < 4; ++grp)
#pragma unroll
      for (int r = 0; r < 4; ++r) {
        const int n2 = (grp << 4) + ((l >> 4) << 2) + r;
        Xs[taddr(n2, l & 15, n)] = f2bf(acc2[grp][r]);
      }
  }
  __syncthreads();

  // ---- S4 per n2: Y = (R2[n2]·T2 + b2)∘v -> tile i2, x=n2
#pragma unroll
  for (int u = 0; u < 8; ++u) {
    fr[u][0] = xfrag(Xs, w * 8 + u, 0, l);
    fr[u][1] = xfrag(Xs, w * 8 + u, 1, l);
  }
  __syncthreads();
#pragma unroll
  for (int u = 0; u < 8; ++u) {
    const int n2 = w * 8 + u;
    unsigned vpk[8], bpk[8];
#pragma unroll
    for (int grp = 0; grp < 4; ++grp) {
      float vt[4], bt[4];
#pragma unroll
      for (int r = 0; r < 4; ++r) {
        const int i2 = (grp << 4) + ((l >> 4) << 2) + r;
        vt[r] = vals[inbase + (size_t)((i2 << 6) + n2) * 512 + (l & 15)];
        bt[r] = b2[(i2 << 6) + n2];
      }
      vpk[grp * 2] = pk2(vt[0], vt[1]); vpk[grp * 2 + 1] = pk2(vt[2], vt[3]);
      bpk[grp * 2] = pk2(bt[0], bt[1]); bpk[grp * 2 + 1] = pk2(bt[2], bt[3]);
    }
    f32x4 acc[4] = {};
    wmm(APK, 3, n2, fr[u][0], fr[u][1], l, acc);
#pragma unroll
    for (int grp = 0; grp < 4; ++grp)
#pragma unroll
      for (int r = 0; r < 4; ++r) {
        const int i2 = (grp << 4) + ((l >> 4) << 2) + r;
        const float vf = pkget(vpk[grp * 2 + (r >> 1)], r & 1);
        const float bf = pkget(bpk[grp * 2 + (r >> 1)], r & 1);
        Xs[taddr(i2, l & 15, n2)] = f2bf((acc[grp][r] + bf) * vf);
      }
  }
  __syncthreads();

  // ---- out: out[bh][d][s] fp32, coalesced; wave w owns d-rows w and w+8
#pragma unroll
  for (int half = 0; half < 2; ++half) {
    const int dl = w + (half << 3);
    float* orow = out + ((size_t)bh * 64 + (dq << 4) + dl) * 4096;
#pragma unroll
    for (int o = 0; o < 16; ++o) {
      const int s4 = (o << 8) + (l << 2);
      uint2 rv = *(const uint2*)&Xs[taddr(s4 >> 6, dl, s4 & 63)];
      float4 ov;
      ov.x = bf2f((u16)(rv.x & 0xffffu));
      ov.y = bf2f((u16)(rv.x >> 16));
      ov.z = bf2f((u16)(rv.y & 0xffffu));
      ov.w = bf2f((u16)(rv.y >> 16));
      *(float4*)(orow + s4) = ov;
    }
  }
}

// ---------------------------------------------------------------------------
extern "C" void kernel_launch(void* const* d_in, const int* in_sizes, int n_in,
                              void* d_out, int out_size, void* d_ws, size_t ws_size,
                              hipStream_t stream) {
  const float* q   = (const float*)d_in[0];
  const float* k   = (const float*)d_in[1];
  const float* v   = (const float*)d_in[2];
  const float* M1L = (const float*)d_in[3];
  const float* M1R = (const float*)d_in[4];
  const float* M2L = (const float*)d_in[5];
  const float* M2R = (const float*)d_in[6];
  const float* b1  = (const float*)d_in[7];
  const float* b2  = (const float*)d_in[8];

  u16* APK = (u16*)d_ws;  // 2 MB packed weights

  k_prep<<<dim3(256, 4), 256, 0, stream>>>(M1L, M1R, M2L, M2R, APK);
  k_mega<<<256, 512, 0, stream>>>(q, k, v, APK, b1, b2, (float*)d_out);
}